// Round 12
// baseline (161.080 us; speedup 1.0000x reference)
//
#include <hip/hip_runtime.h>

// Camera back-projection R12: R10/R11 champion structure, lanes = 32ix x 2iy.
//
// R11 (pipelining) was neutral -> gather latency already hidden; remaining
// suspect is L1 gather TRANSACTION rate: 16ix x 4iy lanes touch 4 image rows
// x 2-3 lines = 8-12 txns per wave gather. R12's 32ix x 2iy touches 2 rows
// x 2-3 lines = 5-6 txns (~45% fewer), same store granularity (8 x 128B
// pieces per wave instr), same 8 blocks/CU (LDS 19.0KB).
//
// In-block tables (R10): U slab 32ix x 128iz (16 exact IEEE divs/thread),
// stride 132 ushorts (264B rows: bank base 2*ix mod 32 -> 2-way only = free);
// V slab 2iy x 128iz. Gather byte offset = ((U&0x7FFF)+V)&0xFFFFF, valid =
// sign(V & U<<16). Epilogue max(fma(-128,|zc-d|,1),0) bit-exact. zc inline:
// cd - fma(iz+0.5, 2^-7, -0.5) exact. absmax 0.0 every round.

#define RES  128
#define IMG  480
#define TS   36     // result tile row stride (floats)
#define US   132    // U slab row stride (ushorts), 264 B rows
#define VS   132    // V slab row stride (uints)

__global__ __launch_bounds__(256, 8) void cbp_main(
    const float* __restrict__ depth, const float* __restrict__ fl,
    const float* __restrict__ cam_dist, float* __restrict__ out, int N)
{
    __shared__ __align__(16) float          s_tile[64 * TS];  // 9216 B
    __shared__ __align__(16) unsigned short s_U[32 * US];     // 8448 B
    __shared__ __align__(16) unsigned       s_V[2 * VS];      // 1056 B

    const int b = blockIdx.x;
    int n, rblk;
    if (N == 16) {                  // XCD-local: 2 depth images per XCD's L2
        const int xcd = b & 7, i = b >> 3;
        n = xcd * 2 + (i >> 8);
        rblk = i & 255;
    } else { n = b >> 8; rblk = b & 255; }
    const int ixg = rblk & 3;       // 32-ix group (0..3)
    const int iyg = rblk >> 2;      // 2-iy group  (0..63)
    const int l   = threadIdx.x;
    const float flv = fl[n];
    const float cd  = cam_dist[n];

    // ---- in-block tables ----
#pragma unroll
    for (int k = 0; k < 16; ++k) {  // U slab: 32 ix rows x 128 iz
        const int e   = l + 256 * k;
        const int row = e >> 7, izt = e & 127;
        const float zc = cd - ((izt + 0.5f) / 128.0f - 0.5f);
        const float x  = (ixg * 32 + row + 0.5f) / 128.0f - 0.5f;
        const float u  = (flv * x) / zc + 239.5f;            // exact IEEE div
        const int   ui = (int)fminf(fmaxf(rintf(u), 0.0f), 479.0f);
        const unsigned uok = (u >= 0.0f) && (u <= 479.0f);
        s_U[row * US + izt] = (unsigned short)((ui << 2) | (uok << 15));
    }
    {   // V slab: 2 iy rows x 128 iz (256 entries, one per thread)
        const int iyt = l >> 7, izt = l & 127;
        const float zc = cd - ((izt + 0.5f) / 128.0f - 0.5f);
        const float y  = (iyg * 2 + iyt + 0.5f) / 128.0f - 0.5f;
        const float v  = (flv * y) / zc + 239.5f;            // exact IEEE div
        const int   vi = (int)fminf(fmaxf(rintf(v), 0.0f), 479.0f);
        const unsigned vok = (v >= 0.0f) && (v <= 479.0f) && (zc > 0.0f);
        s_V[iyt * VS + izt] = (unsigned)(vi * (IMG * 4)) | (vok << 31);
    }
    __syncthreads();

    const int ix_l = l & 31, iy_l = (l >> 5) & 1, w = l >> 6;
    const int trow = ix_l * 2 + iy_l;
    const char* __restrict__ dbase = (const char*)(depth + (size_t)n * (IMG * IMG));
    // out base: (n, ix = ixg*32, iy = iyg*2, iz = 0)
    const size_t obase = ((size_t)((n << 7) + ixg * 32) << 7 | (iyg * 2)) << 7;

    for (int c = 0; c < 4; ++c) {
        // ---- compute: lanes = 32 ix x 2 iy, iz wave-uniform per instr ----
#pragma unroll
        for (int g = 0; g < 2; ++g) {
            const int jq  = w * 2 + g;          // iz quad slot (0..7)
            const int izc = c * 32 + jq * 4;    // global iz of quad
            const ushort4 pu4 = *(const ushort4*)&s_U[ix_l * US + izc];
            const uint4   pv4 = *(const uint4*)&s_V[iy_l * VS + izc];
            const unsigned pua[4] = {pu4.x, pu4.y, pu4.z, pu4.w};
            const unsigned pva[4] = {pv4.x, pv4.y, pv4.z, pv4.w};
            float4 rr; float* rp = &rr.x;
#pragma unroll
            for (int j = 0; j < 4; ++j) {
                const int   iz = izc + j;
                const float z  = fmaf((float)iz + 0.5f, 0.0078125f, -0.5f); // exact
                const float zc = cd - z;
                const unsigned off = ((pua[j] & 0x7FFFu) + pva[j]) & 0xFFFFFu;
                const float d  = *(const float*)(dbase + off);   // 2-row gather
                const bool ok  = (int)(pva[j] & (pua[j] << 16)) < 0;
                const float v  = fmaxf(fmaf(-128.0f, fabsf(zc - d), 1.0f), 0.0f);
                rp[j] = ok ? v : 0.0f;
            }
            *(float4*)&s_tile[trow * TS + jq * 4] = rr;   // b128, bank floor
        }
        __syncthreads();

        // ---- store: 2 float4/thread; wave instr = 8 x 128B pieces ----
#pragma unroll
        for (int s = 0; s < 2; ++s) {
            const int f  = l + 256 * s;          // 0..511
            const int rw = f >> 3, q = f & 7;    // tile row, iz quad
            const float4 val = *(const float4*)&s_tile[rw * TS + q * 4];
            const int ix2 = rw >> 1, iy2 = rw & 1;
            *(float4*)&out[obase + ((size_t)ix2 << 14) + (iy2 << 7) + c * 32 + q * 4] = val;
        }
        __syncthreads();
    }
}

extern "C" void kernel_launch(void* const* d_in, const int* in_sizes, int n_in,
                              void* d_out, int out_size, void* d_ws, size_t ws_size,
                              hipStream_t stream) {
    const float* depth = (const float*)d_in[0];
    const float* fl    = (const float*)d_in[1];
    const float* cd    = (const float*)d_in[2];
    float* out         = (float*)d_out;

    const int N = in_sizes[1];                     // fl is (N,1)
    cbp_main<<<N * 256, 256, 0, stream>>>(depth, fl, cd, out, N);
}

// Round 13
// 157.278 us; speedup vs baseline: 1.0242x; 1.0242x over previous
//
#include <hip/hip_runtime.h>

// Camera back-projection R13: R11 champion + write-locality block ordering.
//
// R11 (~47us kernel): in-block tables in LDS, lanes = 16ix x 4iy, 32-iz
// chunks through a 9.2KB LDS tile (b128 bank floor), software-pipelined
// gathers, 8 blocks/CU. R12 (lane reshape) regressed -> 16x4 restored.
//
// R13 changes ONLY the rblk->(ixg,iyg) mapping: ixg = rblk>>5, iyg = rblk&31
// (was ixg = rblk&7, iyg = rblk>>3). Each block writes 16 chunks of 2KB at
// 64KB stride; with the old mapping the ~32 concurrent blocks per XCD shared
// iyg across DIFFERENT ix-slabs -> 2KB chunks scattered over 8MB -> DRAM saw
// a quasi-random 2KB write stream (~55% efficiency, the residual ~25us).
// New mapping: concurrent blocks = all 32 iy-groups of ONE 16-ix slab ->
// their chunks tile a 1MB contiguous region -> L2 evictions cluster into
// long DRAM row runs (fillBuffer-style, 6.5 TB/s demonstrated).
//
// Numerics (absmax 0.0 every round): exact IEEE '/' + rintf half-to-even in
// the reference's op order; U = ui<<2|uok<<15, V = vi*1920|vok<<31;
// offset = ((U&0x7FFF)+V)&0xFFFFF, valid = sign(V & U<<16); epilogue
// max(fma(-128,|zc-d|,1),0) == 1-128*min(|zc-d|,1/128) exactly; zc inline
// via exact fma; d>0 folds into the truncation branch (zc >= 1.70).

#define RES  128
#define IMG  480
#define TS   36     // result tile row stride (floats)
#define US   136    // U slab row stride (ushorts)
#define VS   132    // V slab row stride (uints)

template<int C>
__device__ __forceinline__ void compute_chunk(
    float* __restrict__ r,
    const unsigned short* __restrict__ sU,
    const unsigned* __restrict__ sV,
    const char* __restrict__ dbase,
    float cd, int ix_l, int iy_l, int w)
{
#pragma unroll
    for (int g = 0; g < 2; ++g) {
        const int jq  = w * 2 + g;           // iz quad slot (0..7)
        const int izc = C * 32 + jq * 4;     // global iz of quad
        const ushort4 pu4 = *(const ushort4*)&sU[ix_l * US + izc];
        const uint4   pv4 = *(const uint4*)&sV[iy_l * VS + izc];
        const unsigned pua[4] = {pu4.x, pu4.y, pu4.z, pu4.w};
        const unsigned pva[4] = {pv4.x, pv4.y, pv4.z, pv4.w};
#pragma unroll
        for (int j = 0; j < 4; ++j) {
            const int   iz = izc + j;
            const float z  = fmaf((float)iz + 0.5f, 0.0078125f, -0.5f); // exact
            const float zc = cd - z;
            const unsigned off = ((pua[j] & 0x7FFFu) + pva[j]) & 0xFFFFFu;
            const float d  = *(const float*)(dbase + off);   // cache-hot gather
            const bool ok  = (int)(pva[j] & (pua[j] << 16)) < 0;
            const float v  = fmaxf(fmaf(-128.0f, fabsf(zc - d), 1.0f), 0.0f);
            r[g * 4 + j] = ok ? v : 0.0f;
        }
    }
}

__global__ __launch_bounds__(256, 8) void cbp_main(
    const float* __restrict__ depth, const float* __restrict__ fl,
    const float* __restrict__ cam_dist, float* __restrict__ out, int N)
{
    __shared__ __align__(16) float          s_tile[64 * TS];  // 9216 B
    __shared__ __align__(16) unsigned short s_U[16 * US];     // 4352 B
    __shared__ __align__(16) unsigned       s_V[4 * VS];      // 2112 B

    const int b = blockIdx.x;
    int n, rblk;
    if (N == 16) {                  // XCD-local: 2 depth images per XCD's L2
        const int xcd = b & 7, i = b >> 3;
        n = xcd * 2 + (i >> 8);
        rblk = i & 255;
    } else { n = b >> 8; rblk = b & 255; }
    const int ixg = rblk >> 5;      // 16-ix group (0..7)  -- slab-major order:
    const int iyg = rblk & 31;      // 4-iy group  (0..31) -- concurrent blocks
                                    //   tile ONE contiguous 1MB ix-slab
    const int l   = threadIdx.x;
    const float flv = fl[n];
    const float cd  = cam_dist[n];

    // ---- in-block tables: 10 exact IEEE divisions per thread ----
#pragma unroll
    for (int k = 0; k < 8; ++k) {   // U slab: 16 ix rows x 128 iz
        const int e   = l + 256 * k;
        const int row = e >> 7, izt = e & 127;
        const float zc = cd - ((izt + 0.5f) / 128.0f - 0.5f);
        const float x  = (ixg * 16 + row + 0.5f) / 128.0f - 0.5f;
        const float u  = (flv * x) / zc + 239.5f;            // exact IEEE div
        const int   ui = (int)fminf(fmaxf(rintf(u), 0.0f), 479.0f);
        const unsigned uok = (u >= 0.0f) && (u <= 479.0f);
        s_U[row * US + izt] = (unsigned short)((ui << 2) | (uok << 15));
    }
#pragma unroll
    for (int k = 0; k < 2; ++k) {   // V slab: 4 iy rows x 128 iz
        const int e   = l + 256 * k;
        const int iyt = e >> 7, izt = e & 127;
        const float zc = cd - ((izt + 0.5f) / 128.0f - 0.5f);
        const float y  = (iyg * 4 + iyt + 0.5f) / 128.0f - 0.5f;
        const float v  = (flv * y) / zc + 239.5f;            // exact IEEE div
        const int   vi = (int)fminf(fmaxf(rintf(v), 0.0f), 479.0f);
        const unsigned vok = (v >= 0.0f) && (v <= 479.0f) && (zc > 0.0f);
        s_V[iyt * VS + izt] = (unsigned)(vi * (IMG * 4)) | (vok << 31);
    }
    __syncthreads();

    const int ix_l = l & 15, iy_l = (l >> 4) & 3, w = l >> 6;
    const int trow = ix_l * 4 + iy_l;
    const char* __restrict__ dbase = (const char*)(depth + (size_t)n * (IMG * IMG));
    const size_t obase = ((size_t)((n << 7) + ixg * 16) << 7 | (iyg * 4)) << 7;

    float r[8];                     // pipelined chunk results (2 float4)
    compute_chunk<0>(r, s_U, s_V, dbase, cd, ix_l, iy_l, w);

#pragma unroll
    for (int c = 0; c < 4; ++c) {
        __syncthreads();            // tile free (prev store-phase reads done)
        *(float4*)&s_tile[trow * TS + (w * 2) * 4]     = *(const float4*)&r[0];
        *(float4*)&s_tile[trow * TS + (w * 2 + 1) * 4] = *(const float4*)&r[4];
        __syncthreads();            // tile full

        // issue next chunk's gathers now; they overlap the store phase below
        if (c == 0) compute_chunk<1>(r, s_U, s_V, dbase, cd, ix_l, iy_l, w);
        else if (c == 1) compute_chunk<2>(r, s_U, s_V, dbase, cd, ix_l, iy_l, w);
        else if (c == 2) compute_chunk<3>(r, s_U, s_V, dbase, cd, ix_l, iy_l, w);

        // store: 2 float4/thread; wave instr = 8 x 128B pieces
#pragma unroll
        for (int s = 0; s < 2; ++s) {
            const int f  = l + 256 * s;          // 0..511
            const int rw = f >> 3, q = f & 7;
            const float4 val = *(const float4*)&s_tile[rw * TS + q * 4];
            const int ix2 = rw >> 2, iy2 = rw & 3;
            *(float4*)&out[obase + ((size_t)ix2 << 14) + (iy2 << 7) + c * 32 + q * 4] = val;
        }
    }
}

extern "C" void kernel_launch(void* const* d_in, const int* in_sizes, int n_in,
                              void* d_out, int out_size, void* d_ws, size_t ws_size,
                              hipStream_t stream) {
    const float* depth = (const float*)d_in[0];
    const float* fl    = (const float*)d_in[1];
    const float* cd    = (const float*)d_in[2];
    float* out         = (float*)d_out;

    const int N = in_sizes[1];                     // fl is (N,1)
    cbp_main<<<N * 256, 256, 0, stream>>>(depth, fl, cd, out, N);
}